// Round 4
// baseline (1353.305 us; speedup 1.0000x reference)
//
#include <hip/hip_runtime.h>

// Net_23484881175023: conv1d(k=3,stride=3) -> LSTM(input=1, hidden=10, T=8192) -> Linear(10,3)
// B=512, L=24576, Lp=8192.
//
// Latency-bound sequential recurrence. Round-4 structure: TWO batch elements
// per wave (registers hA/csA and hB/csB, same 40-lane gate layout). The two
// recurrence chains are independent; the compiler interleaves them so one
// batch's instructions issue inside the other's dependency stalls (trans-op
// latency, readlane->SGPR hazard slots, DPP cross-lane latency). Chain length
// per step ~= 215 cyc >> issue cost of 2 steps (~160 cyc), so the wave retires
// 2 batches per chain traversal -> ~2x.
//
// Per-step math (per batch): h-dot via packed f16 dot2 (4 readlanes of packed
// pairs + f32 head), unified sigmoid activation with smul folded into weights,
// pre-scaled cell state cs = -2*log2e*c, quad DPP gathers for i/f/g/o.

#define DEV __device__ __forceinline__

typedef _Float16 half2v __attribute__((ext_vector_type(2)));

DEV float rl_f(float v, int lane) {
  return __int_as_float(__builtin_amdgcn_readlane(__float_as_int(v), lane));
}

DEV half2v rl_h2(half2v v, int lane) {
  int i = __builtin_amdgcn_readlane(__builtin_bit_cast(int, v), lane);
  return __builtin_bit_cast(half2v, i);
}

DEV half2v pkrtz(float a, float b) {
  return __builtin_bit_cast(half2v, __builtin_amdgcn_cvt_pkrtz(a, b));
}

template <int CTRL>
DEV float dpp_f(float v) {
#if __has_builtin(__builtin_amdgcn_mov_dpp)
  return __int_as_float(__builtin_amdgcn_mov_dpp(__float_as_int(v), CTRL, 0xF, 0xF, true));
#else
  return __int_as_float(__builtin_amdgcn_update_dpp(0, __float_as_int(v), CTRL, 0xF, 0xF, true));
#endif
}

DEV float fast_exp2(float x) {
#if __has_builtin(__builtin_amdgcn_exp2f)
  return __builtin_amdgcn_exp2f(x);
#else
  return __exp2f(x);
#endif
}

DEV float fast_rcp(float x) { return __builtin_amdgcn_rcpf(x); }

#if __has_builtin(__builtin_amdgcn_fdot2)
#define USE_FDOT2 1
#else
#define USE_FDOT2 0
#endif

constexpr int kB = 512;
constexpr int kL = 24576;
constexpr int kLp = 8192;      // kL / 3
constexpr int kHid = 10;
constexpr int kChunk = 64;     // timesteps per chunk (one ct per lane)
constexpr int kNChunk = kLp / kChunk;  // 128

__global__ __launch_bounds__(64, 1) void lstm_fused(
    const float* __restrict__ x,       // (B, L, 1)
    const float* __restrict__ conv_w,  // (1,1,3)
    const float* __restrict__ conv_b,  // (1,)
    const float* __restrict__ w_ih,    // (40,1)
    const float* __restrict__ w_hh,    // (40,10)
    const float* __restrict__ b_ih,    // (40,)
    const float* __restrict__ b_hh,    // (40,)
    const float* __restrict__ mlp_w,   // (3,10)
    const float* __restrict__ mlp_b,   // (3,)
    float* __restrict__ out) {         // (B,3)
  const int lane = threadIdx.x & 63;
  const int bA = blockIdx.x * 2;
  const int bB = bA + 1;

  const int hid = lane >> 2;   // 0..9 for active lanes
  const int gt = lane & 3;     // 0:i 1:f 2:g 3:o (torch gate order)
  const bool active = (lane < 40);
  const int r = active ? (gt * kHid + hid) : 0;  // row in the 4H-stacked weights

  // uniform conv params (scalar loads)
  const float cw0 = conv_w[0], cw1 = conv_w[1], cw2 = conv_w[2];
  const float cbv = conv_b[0];

  constexpr float kL2E = 1.4426950408889634f;  // log2(e)
  // gate g uses sigmoid(2x) (tanh folding); i/f/o use sigmoid(x).
  // Fold the exp2 scale into the weights so the dot feeds exp2 directly.
  const float smul = (gt == 2) ? (-2.0f * kL2E) : (-kL2E);

  const float wih = w_ih[r] * smul;
  const float bsum = (b_ih[r] + b_hh[r]) * smul;
  const float* wr = w_hh + r * kHid;
  const float w0s = wr[0] * smul, w1s = wr[1] * smul;
  const float w2s = wr[2] * smul, w3s = wr[3] * smul, w4s = wr[4] * smul;
  const float w5s = wr[5] * smul, w6s = wr[6] * smul, w7s = wr[7] * smul;
  const float w8s = wr[8] * smul, w9s = wr[9] * smul;

#if USE_FDOT2
  const half2v wp1 = pkrtz(w2s, w3s);
  const half2v wp2 = pkrtz(w4s, w5s);
  const half2v wp3 = pkrtz(w6s, w7s);
  const half2v wp4 = pkrtz(w8s, w9s);
#endif

  // cell-update constants (cs = -2*log2e * c is the tracked state):
  //   cs_new = f*cs + C2*i + C4*i*g,  C4 = -4*log2e, C2 = 2*log2e
  const float C4 = -4.0f * kL2E;
  const float C2 = 2.0f * kL2E;

  const float* xbA = x + (size_t)bA * kL;
  const float* xbB = x + (size_t)bB * kL;
  const int xoff = lane * 3;

  // prefetch chunk 0's x values for both batches
  float x0A = xbA[xoff + 0], x1A = xbA[xoff + 1], x2A = xbA[xoff + 2];
  float x0B = xbB[xoff + 0], x1B = xbB[xoff + 1], x2B = xbB[xoff + 2];

  float hA = 0.0f, csA = 0.0f;  // batch A state (quad value of h[hid], scaled c)
  float hB = 0.0f, csB = 0.0f;  // batch B state

  // One LSTM step for one batch element's (h, cs) given the conv output ct of
  // timestep t (held in lane t). Fully inlined; A/B calls are independent and
  // get interleaved by the scheduler.
  auto step = [&](float& h, float& cs, float ct, int t) {
    const float ctv = rl_f(ct, t);
    const float xg = fmaf(ctv, wih, bsum);
#if USE_FDOT2
    const float h0 = rl_f(h, 0), h1 = rl_f(h, 4);
    const float hnb = dpp_f<0x104>(h);  // row_shl:4 (lane i <- i+4)
    const half2v hpk = pkrtz(h, hnb);   // (h_{2j}, h_{2j+1}) in even-hid quads
    const half2v p23 = rl_h2(hpk, 8);
    const half2v p45 = rl_h2(hpk, 16);
    const half2v p67 = rl_h2(hpk, 24);
    const half2v p89 = rl_h2(hpk, 32);
    float pA = fmaf(h0, w0s, xg);
    pA = fmaf(h1, w1s, pA);
    pA = __builtin_amdgcn_fdot2(p23, wp1, pA, false);
    float pB = __builtin_amdgcn_fdot2(p45, wp2, 0.0f, false);
    pB = __builtin_amdgcn_fdot2(p67, wp3, pB, false);
    const float pC = __builtin_amdgcn_fdot2(p89, wp4, 0.0f, false);
    const float pre = (pA + pC) + pB;
#else
    const float h0 = rl_f(h, 0), h1 = rl_f(h, 4), h2 = rl_f(h, 8);
    const float h3 = rl_f(h, 12), h4 = rl_f(h, 16), h5 = rl_f(h, 20);
    const float h6 = rl_f(h, 24), h7 = rl_f(h, 28), h8 = rl_f(h, 32);
    const float h9 = rl_f(h, 36);
    float pA = fmaf(h0, w0s, xg);
    pA = fmaf(h1, w1s, pA);
    pA = fmaf(h2, w2s, pA);
    float pB = h3 * w3s;
    pB = fmaf(h4, w4s, pB);
    pB = fmaf(h5, w5s, pB);
    float pC = h6 * w6s;
    pC = fmaf(h7, w7s, pC);
    float pD = h8 * w8s;
    pD = fmaf(h9, w9s, pD);
    const float pre = (pA + pB) + (pC + pD);
#endif
    // a = sigmoid(pre) for i/f/o lanes, sigmoid(2*pre) for g lanes
    const float a = fast_rcp(1.0f + fast_exp2(pre));
    const float iv = dpp_f<0x00>(a);
    const float fv = dpp_f<0x55>(a);
    const float gv = dpp_f<0xAA>(a);  // sigma(2g); tanh(g) = 2*gv - 1
    const float ov = dpp_f<0xFF>(a);
    const float ov2 = ov + ov;  // off-path
    const float ti = iv * C2;
    const float pig = iv * gv;
    const float csp = fmaf(fv, cs, ti);  // parallel with pig
    cs = fmaf(pig, C4, csp);
    // h = o*tanh(c) = fma(sigma(2c), 2o, -o)
    const float s2 = fast_rcp(1.0f + fast_exp2(cs));
    h = fmaf(s2, ov2, -ov);
  };

  for (int ch = 0; ch < kNChunk; ++ch) {
    // conv outputs for timesteps (ch*64 + lane), both batches, all 64 lanes
    float ctA = fmaf(x2A, cw2, fmaf(x1A, cw1, fmaf(x0A, cw0, cbv)));
    ctA = fmaxf(ctA, 0.0f);
    float ctB = fmaf(x2B, cw2, fmaf(x1B, cw1, fmaf(x0B, cw0, cbv)));
    ctB = fmaxf(ctB, 0.0f);

    // prefetch next chunk (consumed after the 64-step inner loop)
    if (ch + 1 < kNChunk) {
      const float* xnA = xbA + (size_t)(ch + 1) * (kChunk * 3) + xoff;
      const float* xnB = xbB + (size_t)(ch + 1) * (kChunk * 3) + xoff;
      x0A = xnA[0]; x1A = xnA[1]; x2A = xnA[2];
      x0B = xnB[0]; x1B = xnB[1]; x2B = xnB[2];
    }

#pragma unroll 4
    for (int t = 0; t < kChunk; ++t) {
      step(hA, csA, ctA, t);
      step(hB, csB, ctB, t);
    }
  }

  // epilogue: out[b][m] = sum_k h[k]*mlp_w[m][k] + mlp_b[m], m = 0..2
  if (lane < 3) {
    const float* mw = mlp_w + lane * kHid;
    float accA = mlp_b[lane], accB = mlp_b[lane];
    accA = fmaf(rl_f(hA, 0), mw[0], accA);
    accB = fmaf(rl_f(hB, 0), mw[0], accB);
    accA = fmaf(rl_f(hA, 4), mw[1], accA);
    accB = fmaf(rl_f(hB, 4), mw[1], accB);
    accA = fmaf(rl_f(hA, 8), mw[2], accA);
    accB = fmaf(rl_f(hB, 8), mw[2], accB);
    accA = fmaf(rl_f(hA, 12), mw[3], accA);
    accB = fmaf(rl_f(hB, 12), mw[3], accB);
    accA = fmaf(rl_f(hA, 16), mw[4], accA);
    accB = fmaf(rl_f(hB, 16), mw[4], accB);
    accA = fmaf(rl_f(hA, 20), mw[5], accA);
    accB = fmaf(rl_f(hB, 20), mw[5], accB);
    accA = fmaf(rl_f(hA, 24), mw[6], accA);
    accB = fmaf(rl_f(hB, 24), mw[6], accB);
    accA = fmaf(rl_f(hA, 28), mw[7], accA);
    accB = fmaf(rl_f(hB, 28), mw[7], accB);
    accA = fmaf(rl_f(hA, 32), mw[8], accA);
    accB = fmaf(rl_f(hB, 32), mw[8], accB);
    accA = fmaf(rl_f(hA, 36), mw[9], accA);
    accB = fmaf(rl_f(hB, 36), mw[9], accB);
    out[bA * 3 + lane] = accA;
    out[bB * 3 + lane] = accB;
  }
}

extern "C" void kernel_launch(void* const* d_in, const int* in_sizes, int n_in,
                              void* d_out, int out_size, void* d_ws, size_t ws_size,
                              hipStream_t stream) {
  const float* x = (const float*)d_in[0];
  const float* conv_w = (const float*)d_in[1];
  const float* conv_b = (const float*)d_in[2];
  const float* w_ih = (const float*)d_in[3];
  const float* w_hh = (const float*)d_in[4];
  const float* b_ih = (const float*)d_in[5];
  const float* b_hh = (const float*)d_in[6];
  const float* mlp_w = (const float*)d_in[7];
  const float* mlp_b = (const float*)d_in[8];
  float* out = (float*)d_out;

  // 256 blocks x 64 threads = 256 waves; TWO batch elements per wave,
  // one wave per CU. Latency-bound: the two recurrences overlap in the
  // wave's stall cycles.
  dim3 grid(kB / 2), block(64);
  hipLaunchKernelGGL(lstm_fused, grid, block, 0, stream, x, conv_w, conv_b,
                     w_ih, w_hh, b_ih, b_hh, mlp_w, mlp_b, out);
}